// Round 2
// baseline (944.768 us; speedup 1.0000x reference)
//
#include <hip/hip_runtime.h>
#include <cstddef>

typedef unsigned short u16;
typedef __attribute__((ext_vector_type(8))) short bf16x8;   // 8 bf16 in 4 VGPRs
typedef __attribute__((ext_vector_type(4))) float f32x4;

__device__ __forceinline__ u16 f2bf(float f) {
  union { float f; unsigned u; } x; x.f = f;
  unsigned r = x.u + 0x7fffu + ((x.u >> 16) & 1u);   // RNE; inputs are finite
  return (u16)(r >> 16);
}
__device__ __forceinline__ float bf2f(u16 h) {
  union { unsigned u; float f; } x; x.u = ((unsigned)h) << 16;
  return x.f;
}

// ---------------------------------------------------------------------------
// f32 -> bf16 elementwise
// ---------------------------------------------------------------------------
__global__ __launch_bounds__(256) void f32_to_bf16(const float* __restrict__ in,
                                                   u16* __restrict__ out, size_t n) {
  size_t i = (size_t)blockIdx.x * 256 + threadIdx.x;
  if (i < n) out[i] = f2bf(in[i]);
}

// ---------------------------------------------------------------------------
// transpose f32 [R][C] -> bf16 [C][R]   (R,C multiples of 32) grid(C/32, R/32)
// ---------------------------------------------------------------------------
__global__ __launch_bounds__(256) void transpose_f32_bf16(const float* __restrict__ in,
                                                          u16* __restrict__ out,
                                                          int R, int C) {
  __shared__ float tile[32][33];
  int c0 = blockIdx.x * 32, r0 = blockIdx.y * 32;
  int tx = threadIdx.x & 31, ty = threadIdx.x >> 5;   // ty: 0..7
  #pragma unroll
  for (int i = ty; i < 32; i += 8)
    tile[i][tx] = in[(size_t)(r0 + i) * C + c0 + tx];
  __syncthreads();
  #pragma unroll
  for (int i = ty; i < 32; i += 8)
    out[(size_t)(c0 + i) * R + r0 + tx] = f2bf(tile[tx][i]);
}

// ---------------------------------------------------------------------------
// GEMM: C[z][M][N] = A[z][M][K] @ Bt[z][N][K]^T   (bf16 in, fp32 accum)
// 128x128 tile, BK=32, 256 thr = 4 waves (2x2), each wave 64x64 via 4x4
// mfma_f32_16x16x32_bf16. M,N mult of 128; K mult of 32.
// ---------------------------------------------------------------------------
enum { EPI_F32 = 0, EPI_BF16 = 1, EPI_BF16_SCALE = 2, EPI_BF16_T = 3,
       EPI_BIAS_RELU_BF16 = 4, EPI_BIAS_F32 = 5 };

#define LDSP 40   // 32 + 8 pad (bf16 elems) -> only 2-way bank aliasing (free, m136)

template <int EPI>
__global__ __launch_bounds__(256) void gemm_bt(
    const u16* __restrict__ A, const u16* __restrict__ Bt, void* __restrict__ Cout,
    const float* __restrict__ bias, int N, int K, int ldc,
    long long sA, long long sB, long long sC)
{
  __shared__ u16 lA[128 * LDSP];
  __shared__ u16 lB[128 * LDSP];

  const int z = blockIdx.z;
  A  += (long long)z * sA;
  Bt += (long long)z * sB;

  const int m0 = blockIdx.y * 128;
  const int n0 = blockIdx.x * 128;

  const int t    = threadIdx.x;
  const int lane = t & 63;
  const int wave = t >> 6;
  const int wm   = (wave >> 1) * 64;
  const int wn   = (wave & 1) * 64;
  const int quad = lane >> 4;     // 0..3
  const int lrow = lane & 15;

  // staging: thread t loads rows (t>>2), (t>>2)+64; 8 bf16 (16B) at col (t&3)*8
  const int arow = t >> 2;
  const int acol = (t & 3) * 8;

  f32x4 acc[4][4];
  const f32x4 zero = {0.f, 0.f, 0.f, 0.f};
  #pragma unroll
  for (int i = 0; i < 4; i++)
    #pragma unroll
    for (int j = 0; j < 4; j++) acc[i][j] = zero;

  for (int k0 = 0; k0 < K; k0 += 32) {
    __syncthreads();
    {
      const uint4 va0 = *(const uint4*)(A  + (size_t)(m0 + arow)      * K + k0 + acol);
      const uint4 va1 = *(const uint4*)(A  + (size_t)(m0 + arow + 64) * K + k0 + acol);
      const uint4 vb0 = *(const uint4*)(Bt + (size_t)(n0 + arow)      * K + k0 + acol);
      const uint4 vb1 = *(const uint4*)(Bt + (size_t)(n0 + arow + 64) * K + k0 + acol);
      *(uint4*)(&lA[(size_t)arow        * LDSP + acol]) = va0;
      *(uint4*)(&lA[(size_t)(arow + 64) * LDSP + acol]) = va1;
      *(uint4*)(&lB[(size_t)arow        * LDSP + acol]) = vb0;
      *(uint4*)(&lB[(size_t)(arow + 64) * LDSP + acol]) = vb1;
    }
    __syncthreads();

    bf16x8 af[4], bfr[4];
    #pragma unroll
    for (int mt = 0; mt < 4; mt++)
      af[mt] = *(const bf16x8*)(&lA[(size_t)(wm + mt * 16 + lrow) * LDSP + quad * 8]);
    #pragma unroll
    for (int nt = 0; nt < 4; nt++)
      bfr[nt] = *(const bf16x8*)(&lB[(size_t)(wn + nt * 16 + lrow) * LDSP + quad * 8]);

    #pragma unroll
    for (int mt = 0; mt < 4; mt++)
      #pragma unroll
      for (int nt = 0; nt < 4; nt++)
        acc[mt][nt] = __builtin_amdgcn_mfma_f32_16x16x32_bf16(af[mt], bfr[nt], acc[mt][nt], 0, 0, 0);
  }

  // epilogue: C/D layout n = lane&15, m = quad*4 + reg (m89-verified)
  #pragma unroll
  for (int mt = 0; mt < 4; mt++) {
    #pragma unroll
    for (int nt = 0; nt < 4; nt++) {
      #pragma unroll
      for (int r = 0; r < 4; r++) {
        const int m = m0 + wm + mt * 16 + quad * 4 + r;
        const int n = n0 + wn + nt * 16 + lrow;
        float v = acc[mt][nt][r];
        size_t idx;
        if constexpr (EPI == EPI_BF16_T) idx = (size_t)z * sC + (size_t)n * ldc + m;
        else                             idx = (size_t)z * sC + (size_t)m * ldc + n;
        if constexpr (EPI == EPI_F32) {
          ((float*)Cout)[idx] = v;
        } else if constexpr (EPI == EPI_BF16 || EPI == EPI_BF16_T) {
          ((u16*)Cout)[idx] = f2bf(v);
        } else if constexpr (EPI == EPI_BF16_SCALE) {
          ((u16*)Cout)[idx] = f2bf(v * 0.03125f);   // 1/sqrt(1024)
        } else if constexpr (EPI == EPI_BIAS_RELU_BF16) {
          v += bias[n];
          ((u16*)Cout)[idx] = f2bf(v > 0.f ? v : 0.f);
        } else {  // EPI_BIAS_F32
          ((float*)Cout)[idx] = v + bias[n];
        }
      }
    }
  }
}

// ---------------------------------------------------------------------------
// in-place row softmax on bf16 scores (already scaled); cols == 2048
// one block (256 thr) per row, 8 contiguous elems/thread (16B load/store)
// ---------------------------------------------------------------------------
__global__ __launch_bounds__(256) void softmax_bf16(u16* __restrict__ SP, int causal) {
  __shared__ float red[8];
  const int row = blockIdx.x;
  const int q = row & 2047;
  u16* p = SP + (size_t)row * 2048;
  const int t = threadIdx.x;
  const int base = t * 8;
  const int limit = causal ? (q + 1) : 2048;

  uint4 raw = *(const uint4*)(p + base);
  unsigned w[4] = {raw.x, raw.y, raw.z, raw.w};
  float v[8];
  #pragma unroll
  for (int j = 0; j < 4; j++) {
    union { unsigned u; float f; } lo, hi;
    lo.u = w[j] << 16; hi.u = w[j] & 0xffff0000u;
    v[2 * j] = lo.f; v[2 * j + 1] = hi.f;
  }
  #pragma unroll
  for (int j = 0; j < 8; j++) if (base + j >= limit) v[j] = -3.4e38f;

  float mx = v[0];
  #pragma unroll
  for (int j = 1; j < 8; j++) mx = fmaxf(mx, v[j]);
  #pragma unroll
  for (int o = 32; o > 0; o >>= 1) mx = fmaxf(mx, __shfl_down(mx, o));
  if ((t & 63) == 0) red[t >> 6] = mx;
  __syncthreads();
  mx = fmaxf(fmaxf(red[0], red[1]), fmaxf(red[2], red[3]));

  float s = 0.f;
  #pragma unroll
  for (int j = 0; j < 8; j++) { float e = __expf(v[j] - mx); v[j] = e; s += e; }
  #pragma unroll
  for (int o = 32; o > 0; o >>= 1) s += __shfl_down(s, o);
  if ((t & 63) == 0) red[4 + (t >> 6)] = s;
  __syncthreads();
  const float inv = 1.f / (red[4] + red[5] + red[6] + red[7]);

  unsigned o4[4];
  #pragma unroll
  for (int j = 0; j < 4; j++)
    o4[j] = (unsigned)f2bf(v[2 * j] * inv) | ((unsigned)f2bf(v[2 * j + 1] * inv) << 16);
  *(uint4*)(p + base) = make_uint4(o4[0], o4[1], o4[2], o4[3]);
}

// ---------------------------------------------------------------------------
// LN(a + b) * g + be ; D == 1024; a is bf16 (ABF=1) or f32 (ABF=0);
// writes f32 to outf if non-null, bf16 to outb if non-null.
// ---------------------------------------------------------------------------
template <int ABF>
__global__ __launch_bounds__(256) void ln_residual(const void* __restrict__ a_,
                                                   const float* __restrict__ b,
                                                   const float* __restrict__ g,
                                                   const float* __restrict__ be,
                                                   float* __restrict__ outf,
                                                   u16* __restrict__ outb) {
  __shared__ float red[8];
  const size_t base = (size_t)blockIdx.x * 1024;
  const int t = threadIdx.x;
  const int i0 = t * 4;

  float va[4];
  if constexpr (ABF) {
    const ushort4 h = *(const ushort4*)((const u16*)a_ + base + i0);
    va[0] = bf2f(h.x); va[1] = bf2f(h.y); va[2] = bf2f(h.z); va[3] = bf2f(h.w);
  } else {
    const float4 f = *(const float4*)((const float*)a_ + base + i0);
    va[0] = f.x; va[1] = f.y; va[2] = f.z; va[3] = f.w;
  }
  const float4 vb = *(const float4*)(b + base + i0);
  float v[4] = {va[0] + vb.x, va[1] + vb.y, va[2] + vb.z, va[3] + vb.w};

  float s = v[0] + v[1] + v[2] + v[3];
  #pragma unroll
  for (int o = 32; o > 0; o >>= 1) s += __shfl_down(s, o);
  if ((t & 63) == 0) red[t >> 6] = s;
  __syncthreads();
  const float mean = (red[0] + red[1] + red[2] + red[3]) * (1.f / 1024.f);

  float qq = 0.f;
  #pragma unroll
  for (int i = 0; i < 4; i++) { float d = v[i] - mean; qq += d * d; }
  #pragma unroll
  for (int o = 32; o > 0; o >>= 1) qq += __shfl_down(qq, o);
  if ((t & 63) == 0) red[4 + (t >> 6)] = qq;
  __syncthreads();
  const float rstd = rsqrtf((red[4] + red[5] + red[6] + red[7]) * (1.f / 1024.f) + 1e-5f);

  const float4 gg = *(const float4*)(g + i0);
  const float4 bb = *(const float4*)(be + i0);
  float y0 = (v[0] - mean) * rstd * gg.x + bb.x;
  float y1 = (v[1] - mean) * rstd * gg.y + bb.y;
  float y2 = (v[2] - mean) * rstd * gg.z + bb.z;
  float y3 = (v[3] - mean) * rstd * gg.w + bb.w;
  if (outf) *(float4*)(outf + base + i0) = make_float4(y0, y1, y2, y3);
  if (outb) {
    ushort4 o4; o4.x = f2bf(y0); o4.y = f2bf(y1); o4.z = f2bf(y2); o4.w = f2bf(y3);
    *(ushort4*)(outb + base + i0) = o4;
  }
}

// ---------------------------------------------------------------------------
extern "C" void kernel_launch(void* const* d_in, const int* in_sizes, int n_in,
                              void* d_out, int out_size, void* d_ws, size_t ws_size,
                              hipStream_t stream)
{
  const float* y_in = (const float*)d_in[0];
  const float* Z_in = (const float*)d_in[1];
  const float* WQ1  = (const float*)d_in[2];
  const float* WK1  = (const float*)d_in[3];
  const float* WV1  = (const float*)d_in[4];
  const float* WQ2  = (const float*)d_in[5];
  const float* WK2  = (const float*)d_in[6];
  const float* WV2  = (const float*)d_in[7];
  const float* Wff1 = (const float*)d_in[8];
  const float* bff1 = (const float*)d_in[9];
  const float* Wff2 = (const float*)d_in[10];
  const float* bff2 = (const float*)d_in[11];
  const float* g1  = (const float*)d_in[12];
  const float* be1 = (const float*)d_in[13];
  const float* g2  = (const float*)d_in[14];
  const float* be2 = (const float*)d_in[15];
  const float* g3  = (const float*)d_in[16];
  const float* be3 = (const float*)d_in[17];
  (void)in_sizes; (void)n_in; (void)out_size;

  constexpr int Bn = 4, S = 2048, D = 1024, DF = 4096;
  constexpr long long BS = (long long)Bn * S;  // 8192 rows
  const long long SD = (long long)S * D, SS = (long long)S * S, DS = (long long)D * S;

  char* ws = (char*)d_ws;
  size_t off = 0;
  auto alloc = [&](size_t bytes) -> char* {
    char* p = ws + off;
    off += (bytes + 255) & ~(size_t)255;
    return p;
  };

  // ---- workspace layout (~172 MB) ----
  u16* wq1t  = (u16*)alloc((size_t)D * D * 2);
  u16* wk1t  = (u16*)alloc((size_t)D * D * 2);
  u16* wv1t  = (u16*)alloc((size_t)D * D * 2);
  u16* wq2t  = (u16*)alloc((size_t)D * D * 2);
  u16* wk2t  = (u16*)alloc((size_t)D * D * 2);
  u16* wv2t  = (u16*)alloc((size_t)D * D * 2);
  u16* wff1t = (u16*)alloc((size_t)D * DF * 2);   // [4096][1024]
  u16* wff2t = (u16*)alloc((size_t)D * DF * 2);   // [1024][4096]
  u16* ybf   = (u16*)alloc((size_t)BS * D * 2);   // X1; reused as y1b after LN1
  u16* zbf   = (u16*)alloc((size_t)BS * D * 2);   // Z;  reused as y2b after LN2
  u16* Qb    = (u16*)alloc((size_t)BS * D * 2);   // |
  u16* Kb    = (u16*)alloc((size_t)BS * D * 2);   // | Qb..SPb (80 MB) reused as
  u16* Vtb   = (u16*)alloc((size_t)Bn * D * S * 2); // | H [8192][4096] bf16 (64 MB)
  u16* SPb   = (u16*)alloc((size_t)Bn * S * S * 2); // | scores/probs bf16, in-place
  float* attnF = (float*)alloc((size_t)BS * D * 4); // attn out f32; reused as F
  u16*   y1b = ybf;
  u16*   y2b = zbf;
  u16*   Hb  = Qb;       // stage-3 hidden, overlays Qb|Kb|Vtb|SPb (all dead)
  float* Fb  = attnF;

  if (off > ws_size) return;   // fail cleanly (absmax) instead of GPU fault

  const dim3 blk(256);

  // ---- input converts + weight transposes (~30 MB traffic, negligible) ----
  f32_to_bf16<<<dim3((unsigned)((BS * D) / 256)), blk, 0, stream>>>(y_in, ybf, (size_t)BS * D);
  f32_to_bf16<<<dim3((unsigned)((BS * D) / 256)), blk, 0, stream>>>(Z_in, zbf, (size_t)BS * D);
  transpose_f32_bf16<<<dim3(D / 32, D / 32), blk, 0, stream>>>(WQ1, wq1t, D, D);
  transpose_f32_bf16<<<dim3(D / 32, D / 32), blk, 0, stream>>>(WK1, wk1t, D, D);
  transpose_f32_bf16<<<dim3(D / 32, D / 32), blk, 0, stream>>>(WV1, wv1t, D, D);
  transpose_f32_bf16<<<dim3(D / 32, D / 32), blk, 0, stream>>>(WQ2, wq2t, D, D);
  transpose_f32_bf16<<<dim3(D / 32, D / 32), blk, 0, stream>>>(WK2, wk2t, D, D);
  transpose_f32_bf16<<<dim3(D / 32, D / 32), blk, 0, stream>>>(WV2, wv2t, D, D);
  transpose_f32_bf16<<<dim3(DF / 32, D / 32), blk, 0, stream>>>(Wff1, wff1t, D, DF);
  transpose_f32_bf16<<<dim3(D / 32, DF / 32), blk, 0, stream>>>(Wff2, wff2t, DF, D);

  // ---- stage 1: causal self-attention + add&norm ----
  gemm_bt<EPI_BF16><<<dim3(D / 128, BS / 128, 1), blk, 0, stream>>>(ybf, wq1t, Qb, nullptr, D, D, D, 0, 0, 0);
  gemm_bt<EPI_BF16><<<dim3(D / 128, BS / 128, 1), blk, 0, stream>>>(ybf, wk1t, Kb, nullptr, D, D, D, 0, 0, 0);
  gemm_bt<EPI_BF16_T><<<dim3(D / 128, S / 128, Bn), blk, 0, stream>>>(ybf, wv1t, Vtb, nullptr, D, D, S, SD, 0, DS);
  gemm_bt<EPI_BF16_SCALE><<<dim3(S / 128, S / 128, Bn), blk, 0, stream>>>(Qb, Kb, SPb, nullptr, S, D, S, SD, SD, SS);
  softmax_bf16<<<dim3((unsigned)(Bn * S)), blk, 0, stream>>>(SPb, 1);
  gemm_bt<EPI_F32><<<dim3(D / 128, S / 128, Bn), blk, 0, stream>>>(SPb, Vtb, attnF, nullptr, D, S, D, SS, DS, SD);
  ln_residual<0><<<dim3((unsigned)BS), blk, 0, stream>>>(y_in, attnF, g1, be1, nullptr, y1b);

  // ---- stage 2: cross-attention + add&norm ----
  gemm_bt<EPI_BF16><<<dim3(D / 128, BS / 128, 1), blk, 0, stream>>>(y1b, wq2t, Qb, nullptr, D, D, D, 0, 0, 0);
  gemm_bt<EPI_BF16><<<dim3(D / 128, BS / 128, 1), blk, 0, stream>>>(zbf, wk2t, Kb, nullptr, D, D, D, 0, 0, 0);
  gemm_bt<EPI_BF16_T><<<dim3(D / 128, S / 128, Bn), blk, 0, stream>>>(zbf, wv2t, Vtb, nullptr, D, D, S, SD, 0, DS);
  gemm_bt<EPI_BF16_SCALE><<<dim3(S / 128, S / 128, Bn), blk, 0, stream>>>(Qb, Kb, SPb, nullptr, S, D, S, SD, SD, SS);
  softmax_bf16<<<dim3((unsigned)(Bn * S)), blk, 0, stream>>>(SPb, 0);
  gemm_bt<EPI_F32><<<dim3(D / 128, S / 128, Bn), blk, 0, stream>>>(SPb, Vtb, attnF, nullptr, D, S, D, SS, DS, SD);
  ln_residual<1><<<dim3((unsigned)BS), blk, 0, stream>>>(y1b, attnF, g2, be2, nullptr, y2b);

  // ---- stage 3: FFN + add&norm ----
  gemm_bt<EPI_BIAS_RELU_BF16><<<dim3(DF / 128, BS / 128, 1), blk, 0, stream>>>(y2b, wff1t, Hb, bff1, DF, D, DF, 0, 0, 0);
  gemm_bt<EPI_BIAS_F32><<<dim3(D / 128, BS / 128, 1), blk, 0, stream>>>(Hb, wff2t, Fb, bff2, D, DF, D, 0, 0, 0);
  ln_residual<1><<<dim3((unsigned)BS), blk, 0, stream>>>(y2b, Fb, g3, be3, (float*)d_out, nullptr);
}

// Round 3
// 886.119 us; speedup vs baseline: 1.0662x; 1.0662x over previous
//
#include <hip/hip_runtime.h>
#include <cstddef>

typedef unsigned short u16;
typedef __attribute__((ext_vector_type(8))) short bf16x8;   // 8 bf16 in 4 VGPRs
typedef __attribute__((ext_vector_type(4))) float f32x4;

__device__ __forceinline__ u16 f2bf(float f) {
  union { float f; unsigned u; } x; x.f = f;
  unsigned r = x.u + 0x7fffu + ((x.u >> 16) & 1u);   // RNE; inputs are finite
  return (u16)(r >> 16);
}
__device__ __forceinline__ float bf2f(u16 h) {
  union { unsigned u; float f; } x; x.u = ((unsigned)h) << 16;
  return x.f;
}

// async global->LDS, 16 B per lane; LDS dest is wave-uniform base + lane*16
__device__ __forceinline__ void gll16(const u16* g, u16* ldsbase) {
  __builtin_amdgcn_global_load_lds(
      (const __attribute__((address_space(1))) void*)g,
      (__attribute__((address_space(3))) void*)ldsbase, 16, 0, 0);
}

// ---------------------------------------------------------------------------
// f32 -> bf16 elementwise
// ---------------------------------------------------------------------------
__global__ __launch_bounds__(256) void f32_to_bf16(const float* __restrict__ in,
                                                   u16* __restrict__ out, size_t n) {
  size_t i = (size_t)blockIdx.x * 256 + threadIdx.x;
  if (i < n) out[i] = f2bf(in[i]);
}

// ---------------------------------------------------------------------------
// transpose f32 [R][C] -> bf16 [C][R]   (R,C multiples of 32) grid(C/32, R/32)
// ---------------------------------------------------------------------------
__global__ __launch_bounds__(256) void transpose_f32_bf16(const float* __restrict__ in,
                                                          u16* __restrict__ out,
                                                          int R, int C) {
  __shared__ float tile[32][33];
  int c0 = blockIdx.x * 32, r0 = blockIdx.y * 32;
  int tx = threadIdx.x & 31, ty = threadIdx.x >> 5;   // ty: 0..7
  #pragma unroll
  for (int i = ty; i < 32; i += 8)
    tile[i][tx] = in[(size_t)(r0 + i) * C + c0 + tx];
  __syncthreads();
  #pragma unroll
  for (int i = ty; i < 32; i += 8)
    out[(size_t)(c0 + i) * R + r0 + tx] = f2bf(tile[tx][i]);
}

// ---------------------------------------------------------------------------
// GEMM: C[z][M][N] = A[z][M][K] @ Bt[z][N][K]^T   (bf16 in, fp32 accum)
// 128x128 tile, BK=32, 256 thr = 4 waves (2x2), each wave 64x64 via 4x4
// mfma_f32_16x16x32_bf16. M,N mult of 128; K mult of 32.
// m97 structure: global_load_lds width-16 staging into PAD-FREE LDS
// (row-major 128x32 bf16, 64 B rows) + XCD-compact block swizzle.
// ---------------------------------------------------------------------------
enum { EPI_F32 = 0, EPI_BF16 = 1, EPI_BF16_SCALE = 2, EPI_BF16_T = 3,
       EPI_BIAS_RELU_BF16 = 4, EPI_BIAS_F32 = 5 };

template <int EPI>
__global__ __launch_bounds__(256) void gemm_bt(
    const u16* __restrict__ A, const u16* __restrict__ Bt, void* __restrict__ Cout,
    const float* __restrict__ bias, int N, int K, int ldc,
    long long sA, long long sB, long long sC)
{
  __shared__ u16 lA[128 * 32];   // 8 KB, unpadded (global_load_lds layout)
  __shared__ u16 lB[128 * 32];

  // ---- XCD-compact swizzle: id%8 is the XCD (round-robin dispatch, m09);
  //      give each XCD a contiguous m-major region of the (z,m,n) tile space.
  const unsigned gx = gridDim.x, gxy = gridDim.x * gridDim.y;
  unsigned id = blockIdx.x + gx * blockIdx.y + gxy * blockIdx.z;
  const unsigned nb = gxy * gridDim.z;
  unsigned p = id;
  if ((nb & 7u) == 0u) p = (id & 7u) * (nb >> 3) + (id >> 3);
  const int z  = p / gxy;
  const unsigned rem = p % gxy;
  const int m0 = (int)(rem / gx) * 128;
  const int n0 = (int)(rem % gx) * 128;

  A  += (long long)z * sA;
  Bt += (long long)z * sB;

  const int t    = threadIdx.x;
  const int lane = t & 63;
  const int wave = t >> 6;
  const int wm   = (wave >> 1) * 64;
  const int wn   = (wave & 1) * 64;
  const int quad = lane >> 4;     // 0..3
  const int lrow = lane & 15;

  // staging: wave w stages rows [w*16, w*16+16); lane -> row w*16+(lane>>2),
  // col (lane&3)*8. HW scatters lane's 16 B at ldsbase + lane*16.
  const int srow = wave * 16 + (lane >> 2);
  const int scol = (lane & 3) * 8;

  const u16* gA = A  + (size_t)(m0 + srow) * K + scol;
  const u16* gB = Bt + (size_t)(n0 + srow) * K + scol;
  u16* lAw = lA + wave * 512;    // wave-uniform LDS dest (16 rows * 32 elems)
  u16* lBw = lB + wave * 512;

  f32x4 acc[4][4];
  const f32x4 zero = {0.f, 0.f, 0.f, 0.f};
  #pragma unroll
  for (int i = 0; i < 4; i++)
    #pragma unroll
    for (int j = 0; j < 4; j++) acc[i][j] = zero;

  for (int k0 = 0; k0 < K; k0 += 32) {
    __syncthreads();
    gll16(gA + k0, lAw);
    gll16(gA + (size_t)64 * K + k0, lAw + 64 * 32);
    gll16(gB + k0, lBw);
    gll16(gB + (size_t)64 * K + k0, lBw + 64 * 32);
    __syncthreads();

    bf16x8 af[4], bfr[4];
    #pragma unroll
    for (int mt = 0; mt < 4; mt++)
      af[mt] = *(const bf16x8*)(&lA[(wm + mt * 16 + lrow) * 32 + quad * 8]);
    #pragma unroll
    for (int nt = 0; nt < 4; nt++)
      bfr[nt] = *(const bf16x8*)(&lB[(wn + nt * 16 + lrow) * 32 + quad * 8]);

    #pragma unroll
    for (int mt = 0; mt < 4; mt++)
      #pragma unroll
      for (int nt = 0; nt < 4; nt++)
        acc[mt][nt] = __builtin_amdgcn_mfma_f32_16x16x32_bf16(af[mt], bfr[nt], acc[mt][nt], 0, 0, 0);
  }

  // epilogue: C/D layout n = lane&15, m = quad*4 + reg (m89-verified)
  #pragma unroll
  for (int mt = 0; mt < 4; mt++) {
    #pragma unroll
    for (int nt = 0; nt < 4; nt++) {
      #pragma unroll
      for (int r = 0; r < 4; r++) {
        const int m = m0 + wm + mt * 16 + quad * 4 + r;
        const int n = n0 + wn + nt * 16 + lrow;
        float v = acc[mt][nt][r];
        size_t idx;
        if constexpr (EPI == EPI_BF16_T) idx = (size_t)z * sC + (size_t)n * ldc + m;
        else                             idx = (size_t)z * sC + (size_t)m * ldc + n;
        if constexpr (EPI == EPI_F32) {
          ((float*)Cout)[idx] = v;
        } else if constexpr (EPI == EPI_BF16 || EPI == EPI_BF16_T) {
          ((u16*)Cout)[idx] = f2bf(v);
        } else if constexpr (EPI == EPI_BF16_SCALE) {
          ((u16*)Cout)[idx] = f2bf(v * 0.03125f);   // 1/sqrt(1024)
        } else if constexpr (EPI == EPI_BIAS_RELU_BF16) {
          v += bias[n];
          ((u16*)Cout)[idx] = f2bf(v > 0.f ? v : 0.f);
        } else {  // EPI_BIAS_F32
          ((float*)Cout)[idx] = v + bias[n];
        }
      }
    }
  }
}

// ---------------------------------------------------------------------------
// in-place row softmax on bf16 scores (already scaled); cols == 2048
// one block (256 thr) per row, 8 contiguous elems/thread (16B load/store)
// ---------------------------------------------------------------------------
__global__ __launch_bounds__(256) void softmax_bf16(u16* __restrict__ SP, int causal) {
  __shared__ float red[8];
  const int row = blockIdx.x;
  const int q = row & 2047;
  u16* p = SP + (size_t)row * 2048;
  const int t = threadIdx.x;
  const int base = t * 8;
  const int limit = causal ? (q + 1) : 2048;

  uint4 raw = *(const uint4*)(p + base);
  unsigned w[4] = {raw.x, raw.y, raw.z, raw.w};
  float v[8];
  #pragma unroll
  for (int j = 0; j < 4; j++) {
    union { unsigned u; float f; } lo, hi;
    lo.u = w[j] << 16; hi.u = w[j] & 0xffff0000u;
    v[2 * j] = lo.f; v[2 * j + 1] = hi.f;
  }
  #pragma unroll
  for (int j = 0; j < 8; j++) if (base + j >= limit) v[j] = -3.4e38f;

  float mx = v[0];
  #pragma unroll
  for (int j = 1; j < 8; j++) mx = fmaxf(mx, v[j]);
  #pragma unroll
  for (int o = 32; o > 0; o >>= 1) mx = fmaxf(mx, __shfl_down(mx, o));
  if ((t & 63) == 0) red[t >> 6] = mx;
  __syncthreads();
  mx = fmaxf(fmaxf(red[0], red[1]), fmaxf(red[2], red[3]));

  float s = 0.f;
  #pragma unroll
  for (int j = 0; j < 8; j++) { float e = __expf(v[j] - mx); v[j] = e; s += e; }
  #pragma unroll
  for (int o = 32; o > 0; o >>= 1) s += __shfl_down(s, o);
  if ((t & 63) == 0) red[4 + (t >> 6)] = s;
  __syncthreads();
  const float inv = 1.f / (red[4] + red[5] + red[6] + red[7]);

  unsigned o4[4];
  #pragma unroll
  for (int j = 0; j < 4; j++)
    o4[j] = (unsigned)f2bf(v[2 * j] * inv) | ((unsigned)f2bf(v[2 * j + 1] * inv) << 16);
  *(uint4*)(p + base) = make_uint4(o4[0], o4[1], o4[2], o4[3]);
}

// ---------------------------------------------------------------------------
// LN(a + b) * g + be ; D == 1024; a is bf16 (ABF=1) or f32 (ABF=0);
// writes f32 to outf if non-null, bf16 to outb if non-null.
// ---------------------------------------------------------------------------
template <int ABF>
__global__ __launch_bounds__(256) void ln_residual(const void* __restrict__ a_,
                                                   const float* __restrict__ b,
                                                   const float* __restrict__ g,
                                                   const float* __restrict__ be,
                                                   float* __restrict__ outf,
                                                   u16* __restrict__ outb) {
  __shared__ float red[8];
  const size_t base = (size_t)blockIdx.x * 1024;
  const int t = threadIdx.x;
  const int i0 = t * 4;

  float va[4];
  if constexpr (ABF) {
    const ushort4 h = *(const ushort4*)((const u16*)a_ + base + i0);
    va[0] = bf2f(h.x); va[1] = bf2f(h.y); va[2] = bf2f(h.z); va[3] = bf2f(h.w);
  } else {
    const float4 f = *(const float4*)((const float*)a_ + base + i0);
    va[0] = f.x; va[1] = f.y; va[2] = f.z; va[3] = f.w;
  }
  const float4 vb = *(const float4*)(b + base + i0);
  float v[4] = {va[0] + vb.x, va[1] + vb.y, va[2] + vb.z, va[3] + vb.w};

  float s = v[0] + v[1] + v[2] + v[3];
  #pragma unroll
  for (int o = 32; o > 0; o >>= 1) s += __shfl_down(s, o);
  if ((t & 63) == 0) red[t >> 6] = s;
  __syncthreads();
  const float mean = (red[0] + red[1] + red[2] + red[3]) * (1.f / 1024.f);

  float qq = 0.f;
  #pragma unroll
  for (int i = 0; i < 4; i++) { float d = v[i] - mean; qq += d * d; }
  #pragma unroll
  for (int o = 32; o > 0; o >>= 1) qq += __shfl_down(qq, o);
  if ((t & 63) == 0) red[4 + (t >> 6)] = qq;
  __syncthreads();
  const float rstd = rsqrtf((red[4] + red[5] + red[6] + red[7]) * (1.f / 1024.f) + 1e-5f);

  const float4 gg = *(const float4*)(g + i0);
  const float4 bb = *(const float4*)(be + i0);
  float y0 = (v[0] - mean) * rstd * gg.x + bb.x;
  float y1 = (v[1] - mean) * rstd * gg.y + bb.y;
  float y2 = (v[2] - mean) * rstd * gg.z + bb.z;
  float y3 = (v[3] - mean) * rstd * gg.w + bb.w;
  if (outf) *(float4*)(outf + base + i0) = make_float4(y0, y1, y2, y3);
  if (outb) {
    ushort4 o4; o4.x = f2bf(y0); o4.y = f2bf(y1); o4.z = f2bf(y2); o4.w = f2bf(y3);
    *(ushort4*)(outb + base + i0) = o4;
  }
}

// ---------------------------------------------------------------------------
extern "C" void kernel_launch(void* const* d_in, const int* in_sizes, int n_in,
                              void* d_out, int out_size, void* d_ws, size_t ws_size,
                              hipStream_t stream)
{
  const float* y_in = (const float*)d_in[0];
  const float* Z_in = (const float*)d_in[1];
  const float* WQ1  = (const float*)d_in[2];
  const float* WK1  = (const float*)d_in[3];
  const float* WV1  = (const float*)d_in[4];
  const float* WQ2  = (const float*)d_in[5];
  const float* WK2  = (const float*)d_in[6];
  const float* WV2  = (const float*)d_in[7];
  const float* Wff1 = (const float*)d_in[8];
  const float* bff1 = (const float*)d_in[9];
  const float* Wff2 = (const float*)d_in[10];
  const float* bff2 = (const float*)d_in[11];
  const float* g1  = (const float*)d_in[12];
  const float* be1 = (const float*)d_in[13];
  const float* g2  = (const float*)d_in[14];
  const float* be2 = (const float*)d_in[15];
  const float* g3  = (const float*)d_in[16];
  const float* be3 = (const float*)d_in[17];
  (void)in_sizes; (void)n_in; (void)out_size;

  constexpr int Bn = 4, S = 2048, D = 1024, DF = 4096;
  constexpr long long BS = (long long)Bn * S;  // 8192 rows
  const long long SD = (long long)S * D, SS = (long long)S * S, DS = (long long)D * S;

  char* ws = (char*)d_ws;
  size_t off = 0;
  auto alloc = [&](size_t bytes) -> char* {
    char* p = ws + off;
    off += (bytes + 255) & ~(size_t)255;
    return p;
  };

  // ---- workspace layout (~172 MB) ----
  u16* wq1t  = (u16*)alloc((size_t)D * D * 2);
  u16* wk1t  = (u16*)alloc((size_t)D * D * 2);
  u16* wv1t  = (u16*)alloc((size_t)D * D * 2);
  u16* wq2t  = (u16*)alloc((size_t)D * D * 2);
  u16* wk2t  = (u16*)alloc((size_t)D * D * 2);
  u16* wv2t  = (u16*)alloc((size_t)D * D * 2);
  u16* wff1t = (u16*)alloc((size_t)D * DF * 2);   // [4096][1024]
  u16* wff2t = (u16*)alloc((size_t)D * DF * 2);   // [1024][4096]
  u16* ybf   = (u16*)alloc((size_t)BS * D * 2);   // X1; reused as y1b after LN1
  u16* zbf   = (u16*)alloc((size_t)BS * D * 2);   // Z;  reused as y2b after LN2
  u16* Qb    = (u16*)alloc((size_t)BS * D * 2);   // |
  u16* Kb    = (u16*)alloc((size_t)BS * D * 2);   // | Qb..SPb (80 MB) reused as
  u16* Vtb   = (u16*)alloc((size_t)Bn * D * S * 2); // | H [8192][4096] bf16 (64 MB)
  u16* SPb   = (u16*)alloc((size_t)Bn * S * S * 2); // | scores/probs bf16, in-place
  float* attnF = (float*)alloc((size_t)BS * D * 4); // attn out f32; reused as F
  u16*   y1b = ybf;
  u16*   y2b = zbf;
  u16*   Hb  = Qb;       // stage-3 hidden, overlays Qb|Kb|Vtb|SPb (all dead)
  float* Fb  = attnF;

  if (off > ws_size) return;   // fail cleanly (absmax) instead of GPU fault

  const dim3 blk(256);

  // ---- input converts + weight transposes (~30 MB traffic, negligible) ----
  f32_to_bf16<<<dim3((unsigned)((BS * D) / 256)), blk, 0, stream>>>(y_in, ybf, (size_t)BS * D);
  f32_to_bf16<<<dim3((unsigned)((BS * D) / 256)), blk, 0, stream>>>(Z_in, zbf, (size_t)BS * D);
  transpose_f32_bf16<<<dim3(D / 32, D / 32), blk, 0, stream>>>(WQ1, wq1t, D, D);
  transpose_f32_bf16<<<dim3(D / 32, D / 32), blk, 0, stream>>>(WK1, wk1t, D, D);
  transpose_f32_bf16<<<dim3(D / 32, D / 32), blk, 0, stream>>>(WV1, wv1t, D, D);
  transpose_f32_bf16<<<dim3(D / 32, D / 32), blk, 0, stream>>>(WQ2, wq2t, D, D);
  transpose_f32_bf16<<<dim3(D / 32, D / 32), blk, 0, stream>>>(WK2, wk2t, D, D);
  transpose_f32_bf16<<<dim3(D / 32, D / 32), blk, 0, stream>>>(WV2, wv2t, D, D);
  transpose_f32_bf16<<<dim3(DF / 32, D / 32), blk, 0, stream>>>(Wff1, wff1t, D, DF);
  transpose_f32_bf16<<<dim3(D / 32, DF / 32), blk, 0, stream>>>(Wff2, wff2t, DF, D);

  // ---- stage 1: causal self-attention + add&norm ----
  gemm_bt<EPI_BF16><<<dim3(D / 128, BS / 128, 1), blk, 0, stream>>>(ybf, wq1t, Qb, nullptr, D, D, D, 0, 0, 0);
  gemm_bt<EPI_BF16><<<dim3(D / 128, BS / 128, 1), blk, 0, stream>>>(ybf, wk1t, Kb, nullptr, D, D, D, 0, 0, 0);
  gemm_bt<EPI_BF16_T><<<dim3(D / 128, S / 128, Bn), blk, 0, stream>>>(ybf, wv1t, Vtb, nullptr, D, D, S, SD, 0, DS);
  gemm_bt<EPI_BF16_SCALE><<<dim3(S / 128, S / 128, Bn), blk, 0, stream>>>(Qb, Kb, SPb, nullptr, S, D, S, SD, SD, SS);
  softmax_bf16<<<dim3((unsigned)(Bn * S)), blk, 0, stream>>>(SPb, 1);
  gemm_bt<EPI_F32><<<dim3(D / 128, S / 128, Bn), blk, 0, stream>>>(SPb, Vtb, attnF, nullptr, D, S, D, SS, DS, SD);
  ln_residual<0><<<dim3((unsigned)BS), blk, 0, stream>>>(y_in, attnF, g1, be1, nullptr, y1b);

  // ---- stage 2: cross-attention + add&norm ----
  gemm_bt<EPI_BF16><<<dim3(D / 128, BS / 128, 1), blk, 0, stream>>>(y1b, wq2t, Qb, nullptr, D, D, D, 0, 0, 0);
  gemm_bt<EPI_BF16><<<dim3(D / 128, BS / 128, 1), blk, 0, stream>>>(zbf, wk2t, Kb, nullptr, D, D, D, 0, 0, 0);
  gemm_bt<EPI_BF16_T><<<dim3(D / 128, S / 128, Bn), blk, 0, stream>>>(zbf, wv2t, Vtb, nullptr, D, D, S, SD, 0, DS);
  gemm_bt<EPI_BF16_SCALE><<<dim3(S / 128, S / 128, Bn), blk, 0, stream>>>(Qb, Kb, SPb, nullptr, S, D, S, SD, SD, SS);
  softmax_bf16<<<dim3((unsigned)(Bn * S)), blk, 0, stream>>>(SPb, 0);
  gemm_bt<EPI_F32><<<dim3(D / 128, S / 128, Bn), blk, 0, stream>>>(SPb, Vtb, attnF, nullptr, D, S, D, SS, DS, SD);
  ln_residual<1><<<dim3((unsigned)BS), blk, 0, stream>>>(y1b, attnF, g2, be2, nullptr, y2b);

  // ---- stage 3: FFN + add&norm ----
  gemm_bt<EPI_BIAS_RELU_BF16><<<dim3(DF / 128, BS / 128, 1), blk, 0, stream>>>(y2b, wff1t, Hb, bff1, DF, D, DF, 0, 0, 0);
  gemm_bt<EPI_BIAS_F32><<<dim3(D / 128, BS / 128, 1), blk, 0, stream>>>(Hb, wff2t, Fb, bff2, D, DF, D, 0, 0, 0);
  ln_residual<1><<<dim3((unsigned)BS), blk, 0, stream>>>(y2b, Fb, g3, be3, (float*)d_out, nullptr);
}

// Round 4
// 879.541 us; speedup vs baseline: 1.0742x; 1.0075x over previous
//
#include <hip/hip_runtime.h>
#include <cstddef>

typedef unsigned short u16;
typedef __attribute__((ext_vector_type(8))) short bf16x8;   // 8 bf16 in 4 VGPRs
typedef __attribute__((ext_vector_type(4))) float f32x4;

__device__ __forceinline__ u16 f2bf(float f) {
  union { float f; unsigned u; } x; x.f = f;
  unsigned r = x.u + 0x7fffu + ((x.u >> 16) & 1u);   // RNE; inputs are finite
  return (u16)(r >> 16);
}
__device__ __forceinline__ float bf2f(u16 h) {
  union { unsigned u; float f; } x; x.u = ((unsigned)h) << 16;
  return x.f;
}

// async global->LDS, 16 B per lane; LDS dest is wave-uniform base + lane*16
__device__ __forceinline__ void gll16(const u16* g, u16* ldsbase) {
  __builtin_amdgcn_global_load_lds(
      (const __attribute__((address_space(1))) void*)g,
      (__attribute__((address_space(3))) void*)ldsbase, 16, 0, 0);
}

// ---------------------------------------------------------------------------
__global__ __launch_bounds__(256) void f32_to_bf16(const float* __restrict__ in,
                                                   u16* __restrict__ out, size_t n) {
  size_t i = (size_t)blockIdx.x * 256 + threadIdx.x;
  if (i < n) out[i] = f2bf(in[i]);
}

// transpose f32 [R][C] -> bf16 [C][R]   (R,C multiples of 32) grid(C/32, R/32)
__global__ __launch_bounds__(256) void transpose_f32_bf16(const float* __restrict__ in,
                                                          u16* __restrict__ out,
                                                          int R, int C) {
  __shared__ float tile[32][33];
  int c0 = blockIdx.x * 32, r0 = blockIdx.y * 32;
  int tx = threadIdx.x & 31, ty = threadIdx.x >> 5;   // ty: 0..7
  #pragma unroll
  for (int i = ty; i < 32; i += 8)
    tile[i][tx] = in[(size_t)(r0 + i) * C + c0 + tx];
  __syncthreads();
  #pragma unroll
  for (int i = ty; i < 32; i += 8)
    out[(size_t)(c0 + i) * R + r0 + tx] = f2bf(tile[tx][i]);
}

// ---------------------------------------------------------------------------
// GEMM: C[z][M][N] = A[z][M][K] @ Bt[z][N][K]^T   (bf16 in, fp32 accum)
// 128x128 tile, BK=32, 4 waves (2x2), wave 64x64 via 4x4 mfma_f32_16x16x32_bf16.
// global_load_lds width-16 staging; XOR-swizzled LDS granules so ds_read_b128
// hits all 8 bank-groups per 8-lane batch (data-volume-minimum cycles).
// ---------------------------------------------------------------------------
enum { EPI_F32 = 0, EPI_BF16 = 1, EPI_BF16_SCALE = 2,
       EPI_SPLIT = 3, EPI_BIAS_RELU_BF16 = 4, EPI_BIAS_F32 = 5 };

template <int EPI>
__global__ __launch_bounds__(256) void gemm_bt(
    const u16* __restrict__ A, const u16* __restrict__ Bt,
    void* __restrict__ C0, void* __restrict__ C1, const float* __restrict__ bias,
    int N, int K, int lda, int ldb, int ldc, int split,
    long long sA, long long sB, int sC)
{
  __shared__ u16 lA[128 * 32];   // 8 KB, physical layout = global_load_lds lane order
  __shared__ u16 lB[128 * 32];

  // XCD-compact swizzle: id%8 is the XCD (round-robin); give each XCD a
  // contiguous region of the (z,m,n) tile space for L2 locality.
  const unsigned gx = gridDim.x, gxy = gridDim.x * gridDim.y;
  unsigned id = blockIdx.x + gx * blockIdx.y + gxy * blockIdx.z;
  const unsigned nb = gxy * gridDim.z;
  unsigned p = id;
  if ((nb & 7u) == 0u) p = (id & 7u) * (nb >> 3) + (id >> 3);
  const int z  = p / gxy;
  const unsigned rem = p % gxy;
  const int m0 = (int)(rem / gx) * 128;
  const int n0 = (int)(rem % gx) * 128;

  A  += (long long)z * sA;
  Bt += (long long)z * sB;

  const int t    = threadIdx.x;
  const int lane = t & 63;
  const int wave = t >> 6;
  const int wm   = (wave >> 1) * 64;
  const int wn   = (wave & 1) * 64;
  const int quad = lane >> 4;     // 0..3
  const int lrow = lane & 15;

  // staging: wave w chunk covers rows [w*16, w*16+16), 4 granules/row.
  // physical granule index p_g = lane&3; it holds global granule p_g ^ ((row>>1)&3).
  const int srow = lane >> 2;                              // row within chunk
  const int scol = ((lane & 3) ^ ((srow >> 1) & 3)) * 8;   // swizzled global col
  const u16* gA = A  + (size_t)(m0 + wave * 16 + srow) * lda + scol;
  const u16* gB = Bt + (size_t)(n0 + wave * 16 + srow) * ldb + scol;
  const size_t a64 = (size_t)64 * lda, b64 = (size_t)64 * ldb;
  u16* lAw = lA + wave * 512;    // 16 rows * 32 elems
  u16* lBw = lB + wave * 512;

  // fragment read: logical (row, quad) sits at physical granule quad ^ ((row>>1)&3)
  const int pq = (quad ^ ((lrow >> 1) & 3)) * 8;

  f32x4 acc[4][4];
  const f32x4 zero = {0.f, 0.f, 0.f, 0.f};
  #pragma unroll
  for (int i = 0; i < 4; i++)
    #pragma unroll
    for (int j = 0; j < 4; j++) acc[i][j] = zero;

  for (int k0 = 0; k0 < K; k0 += 32) {
    __syncthreads();
    gll16(gA + k0, lAw);
    gll16(gA + a64 + k0, lAw + 64 * 32);
    gll16(gB + k0, lBw);
    gll16(gB + b64 + k0, lBw + 64 * 32);
    __syncthreads();

    bf16x8 af[4], bfr[4];
    #pragma unroll
    for (int mt = 0; mt < 4; mt++)
      af[mt] = *(const bf16x8*)(&lA[(wm + mt * 16 + lrow) * 32 + pq]);
    #pragma unroll
    for (int nt = 0; nt < 4; nt++)
      bfr[nt] = *(const bf16x8*)(&lB[(wn + nt * 16 + lrow) * 32 + pq]);

    #pragma unroll
    for (int mt = 0; mt < 4; mt++)
      #pragma unroll
      for (int nt = 0; nt < 4; nt++)
        acc[mt][nt] = __builtin_amdgcn_mfma_f32_16x16x32_bf16(af[mt], bfr[nt], acc[mt][nt], 0, 0, 0);
  }

  // epilogue: C/D layout n = lane&15, m = quad*4 + reg (m89-verified).
  // all output buffers < 2^31 elems -> 32-bit address math.
  const unsigned zoff = (unsigned)z * (unsigned)sC;
  #pragma unroll
  for (int mt = 0; mt < 4; mt++) {
    #pragma unroll
    for (int nt = 0; nt < 4; nt++) {
      const int row0 = m0 + wm + mt * 16 + quad * 4;
      const int col  = n0 + wn + nt * 16 + lrow;
      if constexpr (EPI == EPI_SPLIT) {
        if (col < split) {        // wave-uniform: col block and split are /16
          const unsigned b0 = (unsigned)row0 * (unsigned)ldc + (unsigned)col;
          #pragma unroll
          for (int r = 0; r < 4; r++)
            ((u16*)C0)[b0 + (unsigned)r * ldc] = f2bf(acc[mt][nt][r]);
        } else {                  // V: write transposed [zp][col-split][s], 4 consec s
          const int zp = row0 >> 11;
          const int s  = row0 & 2047;
          const unsigned vo = (unsigned)zp * (unsigned)sC
                            + (unsigned)(col - split) * 2048u + (unsigned)s;
          ushort4 o4;
          o4.x = f2bf(acc[mt][nt][0]); o4.y = f2bf(acc[mt][nt][1]);
          o4.z = f2bf(acc[mt][nt][2]); o4.w = f2bf(acc[mt][nt][3]);
          *(ushort4*)((u16*)C1 + vo) = o4;
        }
      } else {
        const unsigned b0 = zoff + (unsigned)row0 * (unsigned)ldc + (unsigned)col;
        #pragma unroll
        for (int r = 0; r < 4; r++) {
          float v = acc[mt][nt][r];
          const unsigned idx = b0 + (unsigned)r * ldc;
          if constexpr (EPI == EPI_F32) {
            ((float*)C0)[idx] = v;
          } else if constexpr (EPI == EPI_BF16) {
            ((u16*)C0)[idx] = f2bf(v);
          } else if constexpr (EPI == EPI_BF16_SCALE) {
            ((u16*)C0)[idx] = f2bf(v * 0.03125f);   // 1/sqrt(1024)
          } else if constexpr (EPI == EPI_BIAS_RELU_BF16) {
            v += bias[col];
            ((u16*)C0)[idx] = f2bf(v > 0.f ? v : 0.f);
          } else {  // EPI_BIAS_F32
            ((float*)C0)[idx] = v + bias[col];
          }
        }
      }
    }
  }
}

// ---------------------------------------------------------------------------
// in-place row softmax on bf16 scores (already scaled); cols == 2048
// ---------------------------------------------------------------------------
__global__ __launch_bounds__(256) void softmax_bf16(u16* __restrict__ SP, int causal) {
  __shared__ float red[8];
  const int row = blockIdx.x;
  const int q = row & 2047;
  u16* p = SP + (size_t)row * 2048;
  const int t = threadIdx.x;
  const int base = t * 8;
  const int limit = causal ? (q + 1) : 2048;

  uint4 raw = *(const uint4*)(p + base);
  unsigned w[4] = {raw.x, raw.y, raw.z, raw.w};
  float v[8];
  #pragma unroll
  for (int j = 0; j < 4; j++) {
    union { unsigned u; float f; } lo, hi;
    lo.u = w[j] << 16; hi.u = w[j] & 0xffff0000u;
    v[2 * j] = lo.f; v[2 * j + 1] = hi.f;
  }
  #pragma unroll
  for (int j = 0; j < 8; j++) if (base + j >= limit) v[j] = -3.4e38f;

  float mx = v[0];
  #pragma unroll
  for (int j = 1; j < 8; j++) mx = fmaxf(mx, v[j]);
  #pragma unroll
  for (int o = 32; o > 0; o >>= 1) mx = fmaxf(mx, __shfl_down(mx, o));
  if ((t & 63) == 0) red[t >> 6] = mx;
  __syncthreads();
  mx = fmaxf(fmaxf(red[0], red[1]), fmaxf(red[2], red[3]));

  float s = 0.f;
  #pragma unroll
  for (int j = 0; j < 8; j++) { float e = __expf(v[j] - mx); v[j] = e; s += e; }
  #pragma unroll
  for (int o = 32; o > 0; o >>= 1) s += __shfl_down(s, o);
  if ((t & 63) == 0) red[4 + (t >> 6)] = s;
  __syncthreads();
  const float inv = 1.f / (red[4] + red[5] + red[6] + red[7]);

  unsigned o4[4];
  #pragma unroll
  for (int j = 0; j < 4; j++)
    o4[j] = (unsigned)f2bf(v[2 * j] * inv) | ((unsigned)f2bf(v[2 * j + 1] * inv) << 16);
  *(uint4*)(p + base) = make_uint4(o4[0], o4[1], o4[2], o4[3]);
}

// ---------------------------------------------------------------------------
// LN(a + b) * g + be ; D == 1024; a bf16 (ABF=1) or f32 (ABF=0)
// ---------------------------------------------------------------------------
template <int ABF>
__global__ __launch_bounds__(256) void ln_residual(const void* __restrict__ a_,
                                                   const float* __restrict__ b,
                                                   const float* __restrict__ g,
                                                   const float* __restrict__ be,
                                                   float* __restrict__ outf,
                                                   u16* __restrict__ outb) {
  __shared__ float red[8];
  const size_t base = (size_t)blockIdx.x * 1024;
  const int t = threadIdx.x;
  const int i0 = t * 4;

  float va[4];
  if constexpr (ABF) {
    const ushort4 h = *(const ushort4*)((const u16*)a_ + base + i0);
    va[0] = bf2f(h.x); va[1] = bf2f(h.y); va[2] = bf2f(h.z); va[3] = bf2f(h.w);
  } else {
    const float4 f = *(const float4*)((const float*)a_ + base + i0);
    va[0] = f.x; va[1] = f.y; va[2] = f.z; va[3] = f.w;
  }
  const float4 vb = *(const float4*)(b + base + i0);
  float v[4] = {va[0] + vb.x, va[1] + vb.y, va[2] + vb.z, va[3] + vb.w};

  float s = v[0] + v[1] + v[2] + v[3];
  #pragma unroll
  for (int o = 32; o > 0; o >>= 1) s += __shfl_down(s, o);
  if ((t & 63) == 0) red[t >> 6] = s;
  __syncthreads();
  const float mean = (red[0] + red[1] + red[2] + red[3]) * (1.f / 1024.f);

  float qq = 0.f;
  #pragma unroll
  for (int i = 0; i < 4; i++) { float d = v[i] - mean; qq += d * d; }
  #pragma unroll
  for (int o = 32; o > 0; o >>= 1) qq += __shfl_down(qq, o);
  if ((t & 63) == 0) red[4 + (t >> 6)] = qq;
  __syncthreads();
  const float rstd = rsqrtf((red[4] + red[5] + red[6] + red[7]) * (1.f / 1024.f) + 1e-5f);

  const float4 gg = *(const float4*)(g + i0);
  const float4 bb = *(const float4*)(be + i0);
  float y0 = (v[0] - mean) * rstd * gg.x + bb.x;
  float y1 = (v[1] - mean) * rstd * gg.y + bb.y;
  float y2 = (v[2] - mean) * rstd * gg.z + bb.z;
  float y3 = (v[3] - mean) * rstd * gg.w + bb.w;
  if (outf) *(float4*)(outf + base + i0) = make_float4(y0, y1, y2, y3);
  if (outb) {
    ushort4 o4; o4.x = f2bf(y0); o4.y = f2bf(y1); o4.z = f2bf(y2); o4.w = f2bf(y3);
    *(ushort4*)(outb + base + i0) = o4;
  }
}

// ---------------------------------------------------------------------------
extern "C" void kernel_launch(void* const* d_in, const int* in_sizes, int n_in,
                              void* d_out, int out_size, void* d_ws, size_t ws_size,
                              hipStream_t stream)
{
  const float* y_in = (const float*)d_in[0];
  const float* Z_in = (const float*)d_in[1];
  const float* WQ1  = (const float*)d_in[2];
  const float* WK1  = (const float*)d_in[3];
  const float* WV1  = (const float*)d_in[4];
  const float* WQ2  = (const float*)d_in[5];
  const float* WK2  = (const float*)d_in[6];
  const float* WV2  = (const float*)d_in[7];
  const float* Wff1 = (const float*)d_in[8];
  const float* bff1 = (const float*)d_in[9];
  const float* Wff2 = (const float*)d_in[10];
  const float* bff2 = (const float*)d_in[11];
  const float* g1  = (const float*)d_in[12];
  const float* be1 = (const float*)d_in[13];
  const float* g2  = (const float*)d_in[14];
  const float* be2 = (const float*)d_in[15];
  const float* g3  = (const float*)d_in[16];
  const float* be3 = (const float*)d_in[17];
  (void)in_sizes; (void)n_in; (void)out_size;

  constexpr int Bn = 4, S = 2048, D = 1024, DF = 4096;
  constexpr long long BS = (long long)Bn * S;  // 8192 rows
  const long long SD = (long long)S * D, SS = (long long)S * S, DS = (long long)D * S;

  char* ws = (char*)d_ws;
  size_t off = 0;
  auto alloc = [&](size_t bytes) -> char* {
    char* p = ws + off;
    off += (bytes + 255) & ~(size_t)255;
    return p;
  };

  // ---- workspace (~172 MB). NOTE: wq1t..wv1t and wk2t..wv2t must stay
  // contiguous (merged-QKV weight views) — sizes are multiples of 256 B.
  u16* wq1t  = (u16*)alloc((size_t)D * D * 2);
  u16* wk1t  = (u16*)alloc((size_t)D * D * 2);
  u16* wv1t  = (u16*)alloc((size_t)D * D * 2);
  u16* wq2t  = (u16*)alloc((size_t)D * D * 2);
  u16* wk2t  = (u16*)alloc((size_t)D * D * 2);
  u16* wv2t  = (u16*)alloc((size_t)D * D * 2);
  u16* wff1t = (u16*)alloc((size_t)D * DF * 2);   // [4096][1024]
  u16* wff2t = (u16*)alloc((size_t)D * DF * 2);   // [1024][4096]
  u16* ybf   = (u16*)alloc((size_t)BS * D * 2);   // X1; reused as y1b after LN1
  u16* zbf   = (u16*)alloc((size_t)BS * D * 2);   // Z;  reused as y2b after LN2
  u16* QKb   = (u16*)alloc((size_t)BS * 2 * D * 2); // [8192][2048]: Q | K
  u16* Vtb   = (u16*)alloc((size_t)Bn * D * S * 2); // [z][1024][2048]
  u16* SPb   = (u16*)alloc((size_t)Bn * S * S * 2); // scores/probs bf16, in-place
  float* attnF = (float*)alloc((size_t)BS * D * 4); // attn out f32; reused as F
  u16*   y1b = ybf;
  u16*   y2b = zbf;
  u16*   Hb  = QKb;      // stage-3 hidden [8192][4096] overlays QKb|Vtb|SPb (dead)
  float* Fb  = attnF;

  if (off > ws_size) return;   // fail cleanly (absmax) instead of GPU fault

  const dim3 blk(256);

  // ---- input converts + weight transposes ----
  f32_to_bf16<<<dim3((unsigned)((BS * D) / 256)), blk, 0, stream>>>(y_in, ybf, (size_t)BS * D);
  f32_to_bf16<<<dim3((unsigned)((BS * D) / 256)), blk, 0, stream>>>(Z_in, zbf, (size_t)BS * D);
  transpose_f32_bf16<<<dim3(D / 32, D / 32), blk, 0, stream>>>(WQ1, wq1t, D, D);
  transpose_f32_bf16<<<dim3(D / 32, D / 32), blk, 0, stream>>>(WK1, wk1t, D, D);
  transpose_f32_bf16<<<dim3(D / 32, D / 32), blk, 0, stream>>>(WV1, wv1t, D, D);
  transpose_f32_bf16<<<dim3(D / 32, D / 32), blk, 0, stream>>>(WQ2, wq2t, D, D);
  transpose_f32_bf16<<<dim3(D / 32, D / 32), blk, 0, stream>>>(WK2, wk2t, D, D);
  transpose_f32_bf16<<<dim3(D / 32, D / 32), blk, 0, stream>>>(WV2, wv2t, D, D);
  transpose_f32_bf16<<<dim3(DF / 32, D / 32), blk, 0, stream>>>(Wff1, wff1t, D, DF);
  transpose_f32_bf16<<<dim3(D / 32, DF / 32), blk, 0, stream>>>(Wff2, wff2t, DF, D);

  // ---- stage 1: causal self-attention + add&norm ----
  // merged QKV: N=3072 (wq1t|wk1t|wv1t contiguous); n<2048 -> QKb, else V^T -> Vtb
  gemm_bt<EPI_SPLIT><<<dim3(3 * D / 128, BS / 128, 1), blk, 0, stream>>>(
      ybf, wq1t, QKb, Vtb, nullptr, 3 * D, D, D, D, 2 * D, 2 * D, 0, 0, (int)DS);
  gemm_bt<EPI_BF16_SCALE><<<dim3(S / 128, S / 128, Bn), blk, 0, stream>>>(
      QKb, QKb + D, SPb, nullptr, nullptr, S, D, 2 * D, 2 * D, S, 0, SD * 2, SD * 2, (int)SS);
  softmax_bf16<<<dim3((unsigned)(Bn * S)), blk, 0, stream>>>(SPb, 1);
  gemm_bt<EPI_F32><<<dim3(D / 128, S / 128, Bn), blk, 0, stream>>>(
      SPb, Vtb, attnF, nullptr, nullptr, D, S, S, S, D, 0, SS, DS, (int)SD);
  ln_residual<0><<<dim3((unsigned)BS), blk, 0, stream>>>(y_in, attnF, g1, be1, nullptr, y1b);

  // ---- stage 2: cross-attention + add&norm ----
  gemm_bt<EPI_BF16><<<dim3(D / 128, BS / 128, 1), blk, 0, stream>>>(
      y1b, wq2t, QKb, nullptr, nullptr, D, D, D, D, 2 * D, 0, 0, 0, 0);
  gemm_bt<EPI_SPLIT><<<dim3(2 * D / 128, BS / 128, 1), blk, 0, stream>>>(
      zbf, wk2t, QKb + D, Vtb, nullptr, 2 * D, D, D, D, 2 * D, D, 0, 0, (int)DS);
  gemm_bt<EPI_BF16_SCALE><<<dim3(S / 128, S / 128, Bn), blk, 0, stream>>>(
      QKb, QKb + D, SPb, nullptr, nullptr, S, D, 2 * D, 2 * D, S, 0, SD * 2, SD * 2, (int)SS);
  softmax_bf16<<<dim3((unsigned)(Bn * S)), blk, 0, stream>>>(SPb, 0);
  gemm_bt<EPI_F32><<<dim3(D / 128, S / 128, Bn), blk, 0, stream>>>(
      SPb, Vtb, attnF, nullptr, nullptr, D, S, S, S, D, 0, SS, DS, (int)SD);
  ln_residual<1><<<dim3((unsigned)BS), blk, 0, stream>>>(y1b, attnF, g2, be2, nullptr, y2b);

  // ---- stage 3: FFN + add&norm ----
  gemm_bt<EPI_BIAS_RELU_BF16><<<dim3(DF / 128, BS / 128, 1), blk, 0, stream>>>(
      y2b, wff1t, Hb, nullptr, bff1, DF, D, D, D, DF, 0, 0, 0, 0);
  gemm_bt<EPI_BIAS_F32><<<dim3(D / 128, BS / 128, 1), blk, 0, stream>>>(
      Hb, wff2t, Fb, nullptr, bff2, D, DF, DF, DF, D, 0, 0, 0, 0);
  ln_residual<1><<<dim3((unsigned)BS), blk, 0, stream>>>(y2b, Fb, g3, be3, (float*)d_out, nullptr);
}

// Round 5
// 843.171 us; speedup vs baseline: 1.1205x; 1.0431x over previous
//
#include <hip/hip_runtime.h>
#include <cstddef>

typedef unsigned short u16;
typedef __attribute__((ext_vector_type(8))) short bf16x8;   // 8 bf16 in 4 VGPRs
typedef __attribute__((ext_vector_type(4))) float f32x4;

__device__ __forceinline__ u16 f2bf(float f) {
  union { float f; unsigned u; } x; x.f = f;
  unsigned r = x.u + 0x7fffu + ((x.u >> 16) & 1u);   // RNE; inputs are finite
  return (u16)(r >> 16);
}
__device__ __forceinline__ float bf2f(u16 h) {
  union { unsigned u; float f; } x; x.u = ((unsigned)h) << 16;
  return x.f;
}

// async global->LDS, 16 B per lane; LDS dest is wave-uniform base + lane*16
__device__ __forceinline__ void gll16(const u16* g, u16* ldsbase) {
  __builtin_amdgcn_global_load_lds(
      (const __attribute__((address_space(1))) void*)g,
      (__attribute__((address_space(3))) void*)ldsbase, 16, 0, 0);
}

// ---------------------------------------------------------------------------
__global__ __launch_bounds__(256) void f32_to_bf16(const float* __restrict__ in,
                                                   u16* __restrict__ out, size_t n) {
  size_t i = (size_t)blockIdx.x * 256 + threadIdx.x;
  if (i < n) out[i] = f2bf(in[i]);
}

// transpose f32 [R][C] -> bf16 [C][R]   (R,C multiples of 32) grid(C/32, R/32)
__global__ __launch_bounds__(256) void transpose_f32_bf16(const float* __restrict__ in,
                                                          u16* __restrict__ out,
                                                          int R, int C) {
  __shared__ float tile[32][33];
  int c0 = blockIdx.x * 32, r0 = blockIdx.y * 32;
  int tx = threadIdx.x & 31, ty = threadIdx.x >> 5;   // ty: 0..7
  #pragma unroll
  for (int i = ty; i < 32; i += 8)
    tile[i][tx] = in[(size_t)(r0 + i) * C + c0 + tx];
  __syncthreads();
  #pragma unroll
  for (int i = ty; i < 32; i += 8)
    out[(size_t)(c0 + i) * R + r0 + tx] = f2bf(tile[tx][i]);
}

// ---------------------------------------------------------------------------
// GEMM: C[z][M][N] = A[z][M][K] @ Bt[z][N][K]^T   (bf16 in, fp32 accum)
// 128x128 tile, BK=32, 4 waves (2x2), wave 64x64 via 4x4 mfma_f32_16x16x32_bf16.
// global_load_lds width-16 staging, XOR-swizzled granules (0 bank conflicts, R4),
// explicit LDS double-buffer w/ one barrier per iter (prefetch overlaps compute).
// Non-split epilogues use operand-swapped MFMA -> lane holds 4 consecutive n
// -> vectorized ushort4/float4 stores.
// ---------------------------------------------------------------------------
enum { EPI_F32 = 0, EPI_BF16 = 1, EPI_BF16_SCALE = 2,
       EPI_SPLIT = 3, EPI_BIAS_RELU_BF16 = 4, EPI_BIAS_F32 = 5 };

template <int EPI>
__global__ __launch_bounds__(256) void gemm_bt(
    const u16* __restrict__ A, const u16* __restrict__ Bt,
    void* __restrict__ C0, void* __restrict__ C1, const float* __restrict__ bias,
    int N, int K, int lda, int ldb, int ldc, int split,
    long long sA, long long sB, int sC)
{
  constexpr bool SW = (EPI != EPI_SPLIT);   // operand-swapped mfma
  __shared__ __align__(16) u16 lA[2][128 * 32];   // 2 x 8 KB double buffer
  __shared__ __align__(16) u16 lB[2][128 * 32];

  // XCD-compact swizzle: id%8 is the XCD (round-robin); give each XCD a
  // contiguous region of the (z,m,n) tile space for L2 locality.
  const unsigned gx = gridDim.x, gxy = gridDim.x * gridDim.y;
  unsigned id = blockIdx.x + gx * blockIdx.y + gxy * blockIdx.z;
  const unsigned nb = gxy * gridDim.z;
  unsigned p = id;
  if ((nb & 7u) == 0u) p = (id & 7u) * (nb >> 3) + (id >> 3);
  const int z  = p / gxy;
  const unsigned rem = p % gxy;
  const int m0 = (int)(rem / gx) * 128;
  const int n0 = (int)(rem % gx) * 128;

  A  += (long long)z * sA;
  Bt += (long long)z * sB;

  const int t    = threadIdx.x;
  const int lane = t & 63;
  const int wave = t >> 6;
  const int wm   = (wave >> 1) * 64;
  const int wn   = (wave & 1) * 64;
  const int quad = lane >> 4;     // 0..3
  const int lrow = lane & 15;

  // staging: wave w chunk covers rows [w*16, w*16+16), 4 granules/row.
  // physical granule p_g = lane&3 holds global granule p_g ^ ((row>>1)&3).
  const int srow = lane >> 2;                              // row within chunk
  const int scol = ((lane & 3) ^ ((srow >> 1) & 3)) * 8;   // swizzled global col
  const u16* gA = A  + (size_t)(m0 + wave * 16 + srow) * lda + scol;
  const u16* gB = Bt + (size_t)(n0 + wave * 16 + srow) * ldb + scol;
  const size_t a64 = (size_t)64 * lda, b64 = (size_t)64 * ldb;
  const int wo = wave * 512;     // wave's chunk offset (16 rows * 32 elems)

  // fragment read: logical (row, quad) sits at physical granule quad ^ ((row>>1)&3)
  const int pq = (quad ^ ((lrow >> 1) & 3)) * 8;

  f32x4 acc[4][4];
  const f32x4 zero = {0.f, 0.f, 0.f, 0.f};
  #pragma unroll
  for (int i = 0; i < 4; i++)
    #pragma unroll
    for (int j = 0; j < 4; j++) acc[i][j] = zero;

  // prefetch tile 0 into buffer 0
  gll16(gA, &lA[0][wo]);
  gll16(gA + a64, &lA[0][wo + 64 * 32]);
  gll16(gB, &lB[0][wo]);
  gll16(gB + b64, &lB[0][wo + 64 * 32]);

  int buf = 0;
  for (int k0 = 0; k0 < K; k0 += 32, buf ^= 1) {
    __syncthreads();   // drains vmcnt: this buffer's prefetch has landed
    if (k0 + 32 < K) { // prefetch next tile into the other buffer
      gll16(gA + k0 + 32, &lA[buf ^ 1][wo]);
      gll16(gA + a64 + k0 + 32, &lA[buf ^ 1][wo + 64 * 32]);
      gll16(gB + k0 + 32, &lB[buf ^ 1][wo]);
      gll16(gB + b64 + k0 + 32, &lB[buf ^ 1][wo + 64 * 32]);
    }

    bf16x8 af[4], bfr[4];
    #pragma unroll
    for (int mt = 0; mt < 4; mt++)
      af[mt] = *(const bf16x8*)(&lA[buf][(wm + mt * 16 + lrow) * 32 + pq]);
    #pragma unroll
    for (int nt = 0; nt < 4; nt++)
      bfr[nt] = *(const bf16x8*)(&lB[buf][(wn + nt * 16 + lrow) * 32 + pq]);

    #pragma unroll
    for (int mt = 0; mt < 4; mt++)
      #pragma unroll
      for (int nt = 0; nt < 4; nt++) {
        if constexpr (SW)
          acc[mt][nt] = __builtin_amdgcn_mfma_f32_16x16x32_bf16(bfr[nt], af[mt], acc[mt][nt], 0, 0, 0);
        else
          acc[mt][nt] = __builtin_amdgcn_mfma_f32_16x16x32_bf16(af[mt], bfr[nt], acc[mt][nt], 0, 0, 0);
      }
  }

  const unsigned zoff = (unsigned)z * (unsigned)sC;
  if constexpr (SW) {
    // swapped C/D layout: lane holds C[m0+wm+mt*16+lrow][nb..nb+3], nb=n0+wn+nt*16+quad*4
    #pragma unroll
    for (int mt = 0; mt < 4; mt++) {
      #pragma unroll
      for (int nt = 0; nt < 4; nt++) {
        const unsigned m  = (unsigned)(m0 + wm + mt * 16 + lrow);
        const unsigned nc = (unsigned)(n0 + wn + nt * 16 + quad * 4);
        const unsigned idx = zoff + m * (unsigned)ldc + nc;
        f32x4 v = acc[mt][nt];
        if constexpr (EPI == EPI_F32) {
          *(float4*)((float*)C0 + idx) = make_float4(v[0], v[1], v[2], v[3]);
        } else if constexpr (EPI == EPI_BF16) {
          ushort4 o; o.x = f2bf(v[0]); o.y = f2bf(v[1]); o.z = f2bf(v[2]); o.w = f2bf(v[3]);
          *(ushort4*)((u16*)C0 + idx) = o;
        } else if constexpr (EPI == EPI_BF16_SCALE) {
          ushort4 o;
          o.x = f2bf(v[0] * 0.03125f); o.y = f2bf(v[1] * 0.03125f);
          o.z = f2bf(v[2] * 0.03125f); o.w = f2bf(v[3] * 0.03125f);
          *(ushort4*)((u16*)C0 + idx) = o;
        } else if constexpr (EPI == EPI_BIAS_RELU_BF16) {
          const float4 bb = *(const float4*)(bias + nc);
          float y0 = v[0] + bb.x, y1 = v[1] + bb.y, y2 = v[2] + bb.z, y3 = v[3] + bb.w;
          ushort4 o;
          o.x = f2bf(y0 > 0.f ? y0 : 0.f); o.y = f2bf(y1 > 0.f ? y1 : 0.f);
          o.z = f2bf(y2 > 0.f ? y2 : 0.f); o.w = f2bf(y3 > 0.f ? y3 : 0.f);
          *(ushort4*)((u16*)C0 + idx) = o;
        } else {  // EPI_BIAS_F32
          const float4 bb = *(const float4*)(bias + nc);
          *(float4*)((float*)C0 + idx) =
              make_float4(v[0] + bb.x, v[1] + bb.y, v[2] + bb.z, v[3] + bb.w);
        }
      }
    }
  } else {
    // EPI_SPLIT, original layout: n = lane&15, m = quad*4 + reg
    #pragma unroll
    for (int mt = 0; mt < 4; mt++) {
      #pragma unroll
      for (int nt = 0; nt < 4; nt++) {
        const int row0 = m0 + wm + mt * 16 + quad * 4;
        const int col  = n0 + wn + nt * 16 + lrow;
        if (col < split) {        // Q/K: wave-uniform branch (16-blocks, split%16==0)
          const unsigned b0 = (unsigned)row0 * (unsigned)ldc + (unsigned)col;
          #pragma unroll
          for (int r = 0; r < 4; r++)
            ((u16*)C0)[b0 + (unsigned)r * ldc] = f2bf(acc[mt][nt][r]);
        } else {                  // V: write transposed [zp][col-split][s], 4 consec s
          const int zp = row0 >> 11;
          const int s  = row0 & 2047;
          const unsigned vo = (unsigned)zp * (unsigned)sC
                            + (unsigned)(col - split) * 2048u + (unsigned)s;
          ushort4 o4;
          o4.x = f2bf(acc[mt][nt][0]); o4.y = f2bf(acc[mt][nt][1]);
          o4.z = f2bf(acc[mt][nt][2]); o4.w = f2bf(acc[mt][nt][3]);
          *(ushort4*)((u16*)C1 + vo) = o4;
        }
      }
    }
  }
}

// ---------------------------------------------------------------------------
// in-place row softmax on bf16 scores (already scaled); cols == 2048
// ---------------------------------------------------------------------------
__global__ __launch_bounds__(256) void softmax_bf16(u16* __restrict__ SP, int causal) {
  __shared__ float red[8];
  const int row = blockIdx.x;
  const int q = row & 2047;
  u16* p = SP + (size_t)row * 2048;
  const int t = threadIdx.x;
  const int base = t * 8;
  const int limit = causal ? (q + 1) : 2048;

  uint4 raw = *(const uint4*)(p + base);
  unsigned w[4] = {raw.x, raw.y, raw.z, raw.w};
  float v[8];
  #pragma unroll
  for (int j = 0; j < 4; j++) {
    union { unsigned u; float f; } lo, hi;
    lo.u = w[j] << 16; hi.u = w[j] & 0xffff0000u;
    v[2 * j] = lo.f; v[2 * j + 1] = hi.f;
  }
  #pragma unroll
  for (int j = 0; j < 8; j++) if (base + j >= limit) v[j] = -3.4e38f;

  float mx = v[0];
  #pragma unroll
  for (int j = 1; j < 8; j++) mx = fmaxf(mx, v[j]);
  #pragma unroll
  for (int o = 32; o > 0; o >>= 1) mx = fmaxf(mx, __shfl_down(mx, o));
  if ((t & 63) == 0) red[t >> 6] = mx;
  __syncthreads();
  mx = fmaxf(fmaxf(red[0], red[1]), fmaxf(red[2], red[3]));

  float s = 0.f;
  #pragma unroll
  for (int j = 0; j < 8; j++) { float e = __expf(v[j] - mx); v[j] = e; s += e; }
  #pragma unroll
  for (int o = 32; o > 0; o >>= 1) s += __shfl_down(s, o);
  if ((t & 63) == 0) red[4 + (t >> 6)] = s;
  __syncthreads();
  const float inv = 1.f / (red[4] + red[5] + red[6] + red[7]);

  unsigned o4[4];
  #pragma unroll
  for (int j = 0; j < 4; j++)
    o4[j] = (unsigned)f2bf(v[2 * j] * inv) | ((unsigned)f2bf(v[2 * j + 1] * inv) << 16);
  *(uint4*)(p + base) = make_uint4(o4[0], o4[1], o4[2], o4[3]);
}

// ---------------------------------------------------------------------------
// LN(a + b) * g + be ; D == 1024; a bf16 (ABF=1) or f32 (ABF=0)
// ---------------------------------------------------------------------------
template <int ABF>
__global__ __launch_bounds__(256) void ln_residual(const void* __restrict__ a_,
                                                   const float* __restrict__ b,
                                                   const float* __restrict__ g,
                                                   const float* __restrict__ be,
                                                   float* __restrict__ outf,
                                                   u16* __restrict__ outb) {
  __shared__ float red[8];
  const size_t base = (size_t)blockIdx.x * 1024;
  const int t = threadIdx.x;
  const int i0 = t * 4;

  float va[4];
  if constexpr (ABF) {
    const ushort4 h = *(const ushort4*)((const u16*)a_ + base + i0);
    va[0] = bf2f(h.x); va[1] = bf2f(h.y); va[2] = bf2f(h.z); va[3] = bf2f(h.w);
  } else {
    const float4 f = *(const float4*)((const float*)a_ + base + i0);
    va[0] = f.x; va[1] = f.y; va[2] = f.z; va[3] = f.w;
  }
  const float4 vb = *(const float4*)(b + base + i0);
  float v[4] = {va[0] + vb.x, va[1] + vb.y, va[2] + vb.z, va[3] + vb.w};

  float s = v[0] + v[1] + v[2] + v[3];
  #pragma unroll
  for (int o = 32; o > 0; o >>= 1) s += __shfl_down(s, o);
  if ((t & 63) == 0) red[t >> 6] = s;
  __syncthreads();
  const float mean = (red[0] + red[1] + red[2] + red[3]) * (1.f / 1024.f);

  float qq = 0.f;
  #pragma unroll
  for (int i = 0; i < 4; i++) { float d = v[i] - mean; qq += d * d; }
  #pragma unroll
  for (int o = 32; o > 0; o >>= 1) qq += __shfl_down(qq, o);
  if ((t & 63) == 0) red[4 + (t >> 6)] = qq;
  __syncthreads();
  const float rstd = rsqrtf((red[4] + red[5] + red[6] + red[7]) * (1.f / 1024.f) + 1e-5f);

  const float4 gg = *(const float4*)(g + i0);
  const float4 bb = *(const float4*)(be + i0);
  float y0 = (v[0] - mean) * rstd * gg.x + bb.x;
  float y1 = (v[1] - mean) * rstd * gg.y + bb.y;
  float y2 = (v[2] - mean) * rstd * gg.z + bb.z;
  float y3 = (v[3] - mean) * rstd * gg.w + bb.w;
  if (outf) *(float4*)(outf + base + i0) = make_float4(y0, y1, y2, y3);
  if (outb) {
    ushort4 o4; o4.x = f2bf(y0); o4.y = f2bf(y1); o4.z = f2bf(y2); o4.w = f2bf(y3);
    *(ushort4*)(outb + base + i0) = o4;
  }
}

// ---------------------------------------------------------------------------
extern "C" void kernel_launch(void* const* d_in, const int* in_sizes, int n_in,
                              void* d_out, int out_size, void* d_ws, size_t ws_size,
                              hipStream_t stream)
{
  const float* y_in = (const float*)d_in[0];
  const float* Z_in = (const float*)d_in[1];
  const float* WQ1  = (const float*)d_in[2];
  const float* WK1  = (const float*)d_in[3];
  const float* WV1  = (const float*)d_in[4];
  const float* WQ2  = (const float*)d_in[5];
  const float* WK2  = (const float*)d_in[6];
  const float* WV2  = (const float*)d_in[7];
  const float* Wff1 = (const float*)d_in[8];
  const float* bff1 = (const float*)d_in[9];
  const float* Wff2 = (const float*)d_in[10];
  const float* bff2 = (const float*)d_in[11];
  const float* g1  = (const float*)d_in[12];
  const float* be1 = (const float*)d_in[13];
  const float* g2  = (const float*)d_in[14];
  const float* be2 = (const float*)d_in[15];
  const float* g3  = (const float*)d_in[16];
  const float* be3 = (const float*)d_in[17];
  (void)in_sizes; (void)n_in; (void)out_size;

  constexpr int Bn = 4, S = 2048, D = 1024, DF = 4096;
  constexpr long long BS = (long long)Bn * S;  // 8192 rows
  const long long SD = (long long)S * D, SS = (long long)S * S, DS = (long long)D * S;

  char* ws = (char*)d_ws;
  size_t off = 0;
  auto alloc = [&](size_t bytes) -> char* {
    char* p = ws + off;
    off += (bytes + 255) & ~(size_t)255;
    return p;
  };

  // ---- workspace (~172 MB). NOTE: wq1t..wv1t and wk2t..wv2t must stay
  // contiguous (merged-QKV weight views) — sizes are multiples of 256 B.
  u16* wq1t  = (u16*)alloc((size_t)D * D * 2);
  u16* wk1t  = (u16*)alloc((size_t)D * D * 2);
  u16* wv1t  = (u16*)alloc((size_t)D * D * 2);
  u16* wq2t  = (u16*)alloc((size_t)D * D * 2);
  u16* wk2t  = (u16*)alloc((size_t)D * D * 2);
  u16* wv2t  = (u16*)alloc((size_t)D * D * 2);
  u16* wff1t = (u16*)alloc((size_t)D * DF * 2);   // [4096][1024]
  u16* wff2t = (u16*)alloc((size_t)D * DF * 2);   // [1024][4096]
  u16* ybf   = (u16*)alloc((size_t)BS * D * 2);   // X1; reused as y1b after LN1
  u16* zbf   = (u16*)alloc((size_t)BS * D * 2);   // Z;  reused as y2b after LN2
  u16* QKb   = (u16*)alloc((size_t)BS * 2 * D * 2); // [8192][2048]: Q | K
  u16* Vtb   = (u16*)alloc((size_t)Bn * D * S * 2); // [z][1024][2048]
  u16* SPb   = (u16*)alloc((size_t)Bn * S * S * 2); // scores/probs bf16, in-place
  float* attnF = (float*)alloc((size_t)BS * D * 4); // attn out f32; reused as F
  u16*   y1b = ybf;
  u16*   y2b = zbf;
  u16*   Hb  = QKb;      // stage-3 hidden [8192][4096] overlays QKb|Vtb|SPb (dead)
  float* Fb  = attnF;

  if (off > ws_size) return;   // fail cleanly (absmax) instead of GPU fault

  const dim3 blk(256);

  // ---- input converts + weight transposes ----
  f32_to_bf16<<<dim3((unsigned)((BS * D) / 256)), blk, 0, stream>>>(y_in, ybf, (size_t)BS * D);
  f32_to_bf16<<<dim3((unsigned)((BS * D) / 256)), blk, 0, stream>>>(Z_in, zbf, (size_t)BS * D);
  transpose_f32_bf16<<<dim3(D / 32, D / 32), blk, 0, stream>>>(WQ1, wq1t, D, D);
  transpose_f32_bf16<<<dim3(D / 32, D / 32), blk, 0, stream>>>(WK1, wk1t, D, D);
  transpose_f32_bf16<<<dim3(D / 32, D / 32), blk, 0, stream>>>(WV1, wv1t, D, D);
  transpose_f32_bf16<<<dim3(D / 32, D / 32), blk, 0, stream>>>(WQ2, wq2t, D, D);
  transpose_f32_bf16<<<dim3(D / 32, D / 32), blk, 0, stream>>>(WK2, wk2t, D, D);
  transpose_f32_bf16<<<dim3(D / 32, D / 32), blk, 0, stream>>>(WV2, wv2t, D, D);
  transpose_f32_bf16<<<dim3(DF / 32, D / 32), blk, 0, stream>>>(Wff1, wff1t, D, DF);
  transpose_f32_bf16<<<dim3(D / 32, DF / 32), blk, 0, stream>>>(Wff2, wff2t, DF, D);

  // ---- stage 1: causal self-attention + add&norm ----
  gemm_bt<EPI_SPLIT><<<dim3(3 * D / 128, BS / 128, 1), blk, 0, stream>>>(
      ybf, wq1t, QKb, Vtb, nullptr, 3 * D, D, D, D, 2 * D, 2 * D, 0, 0, (int)DS);
  gemm_bt<EPI_BF16_SCALE><<<dim3(S / 128, S / 128, Bn), blk, 0, stream>>>(
      QKb, QKb + D, SPb, nullptr, nullptr, S, D, 2 * D, 2 * D, S, 0, SD * 2, SD * 2, (int)SS);
  softmax_bf16<<<dim3((unsigned)(Bn * S)), blk, 0, stream>>>(SPb, 1);
  gemm_bt<EPI_F32><<<dim3(D / 128, S / 128, Bn), blk, 0, stream>>>(
      SPb, Vtb, attnF, nullptr, nullptr, D, S, S, S, D, 0, SS, DS, (int)SD);
  ln_residual<0><<<dim3((unsigned)BS), blk, 0, stream>>>(y_in, attnF, g1, be1, nullptr, y1b);

  // ---- stage 2: cross-attention + add&norm ----
  gemm_bt<EPI_BF16><<<dim3(D / 128, BS / 128, 1), blk, 0, stream>>>(
      y1b, wq2t, QKb, nullptr, nullptr, D, D, D, D, 2 * D, 0, 0, 0, 0);
  gemm_bt<EPI_SPLIT><<<dim3(2 * D / 128, BS / 128, 1), blk, 0, stream>>>(
      zbf, wk2t, QKb + D, Vtb, nullptr, 2 * D, D, D, D, 2 * D, D, 0, 0, (int)DS);
  gemm_bt<EPI_BF16_SCALE><<<dim3(S / 128, S / 128, Bn), blk, 0, stream>>>(
      QKb, QKb + D, SPb, nullptr, nullptr, S, D, 2 * D, 2 * D, S, 0, SD * 2, SD * 2, (int)SS);
  softmax_bf16<<<dim3((unsigned)(Bn * S)), blk, 0, stream>>>(SPb, 0);
  gemm_bt<EPI_F32><<<dim3(D / 128, S / 128, Bn), blk, 0, stream>>>(
      SPb, Vtb, attnF, nullptr, nullptr, D, S, S, S, D, 0, SS, DS, (int)SD);
  ln_residual<1><<<dim3((unsigned)BS), blk, 0, stream>>>(y1b, attnF, g2, be2, nullptr, y2b);

  // ---- stage 3: FFN + add&norm ----
  gemm_bt<EPI_BIAS_RELU_BF16><<<dim3(DF / 128, BS / 128, 1), blk, 0, stream>>>(
      y2b, wff1t, Hb, nullptr, bff1, DF, D, D, D, DF, 0, 0, 0, 0);
  gemm_bt<EPI_BIAS_F32><<<dim3(D / 128, BS / 128, 1), blk, 0, stream>>>(
      Hb, wff2t, Fb, nullptr, bff2, D, DF, DF, DF, D, 0, 0, 0, 0);
  ln_residual<1><<<dim3((unsigned)BS), blk, 0, stream>>>(y2b, Fb, g3, be3, (float*)d_out, nullptr);
}